// Round 18
// baseline (181.320 us; speedup 1.0000x reference)
//
#include <hip/hip_runtime.h>
#include <hip/hip_bf16.h>

typedef __bf16 bf16x8 __attribute__((ext_vector_type(8)));
typedef float  f32x4  __attribute__((ext_vector_type(4)));

__device__ __forceinline__ unsigned short f2bf(float f) {
    union { float f; unsigned int u; } v; v.f = f;
    unsigned int r = v.u + 0x7FFFu + ((v.u >> 16) & 1u);
    return (unsigned short)(r >> 16);
}
__device__ __forceinline__ float bf2f(unsigned short h) {
    union { unsigned int u; float f; } v; v.u = ((unsigned int)h) << 16; return v.f;
}

__device__ __forceinline__ void async16(const unsigned short* g, unsigned short* l) {
    __builtin_amdgcn_global_load_lds(
        (const __attribute__((address_space(1))) unsigned int*)g,
        (__attribute__((address_space(3))) unsigned int*)l,
        16, 0, 0);
}

// ---------------------------------------------------------------------------
// Transpose + cast + mod-4 pack: Xt[n][pi4(m)] = (bf16) X[m][n]
// pi4: [m%4==0 -> m/4 | m%4==2 -> 1024+m/4 | m odd -> 2048+m/2]
// ---------------------------------------------------------------------------
__global__ __launch_bounds__(256) void transpose_perm4(
    const float* __restrict__ X, unsigned short* __restrict__ Xt)
{
    __shared__ float tile[64][65];
    const int bx = blockIdx.x * 64;   // n base
    const int by = blockIdx.y * 64;   // m base
    const int tid = threadIdx.x;

    const int c4 = (tid & 15) * 4;
    const int r  = tid >> 4;
#pragma unroll
    for (int p = 0; p < 4; ++p) {
        const float4 v = *reinterpret_cast<const float4*>(
            &X[(size_t)(by + r + 16 * p) * 4096 + bx + c4]);
        tile[r + 16 * p][c4 + 0] = v.x;
        tile[r + 16 * p][c4 + 1] = v.y;
        tile[r + 16 * p][c4 + 2] = v.z;
        tile[r + 16 * p][c4 + 3] = v.w;
    }
    __syncthreads();

    const int g  = tid & 15;
    const int n0 = tid >> 4;
#pragma unroll
    for (int p = 0; p < 4; ++p) {
        const int n = n0 + 16 * p;
        unsigned short* row = Xt + (size_t)(bx + n) * 4096;
        ushort4 o;
        if (g < 4) {                       // ee: m = by+16g+4e
            o.x = f2bf(tile[16 * g + 0][n]);
            o.y = f2bf(tile[16 * g + 4][n]);
            o.z = f2bf(tile[16 * g + 8][n]);
            o.w = f2bf(tile[16 * g + 12][n]);
            *reinterpret_cast<ushort4*>(row + (by >> 2) + 4 * g) = o;
        } else if (g < 8) {                // eo: m = by+16g2+4e+2
            const int g2 = g - 4;
            o.x = f2bf(tile[16 * g2 + 2][n]);
            o.y = f2bf(tile[16 * g2 + 6][n]);
            o.z = f2bf(tile[16 * g2 + 10][n]);
            o.w = f2bf(tile[16 * g2 + 14][n]);
            *reinterpret_cast<ushort4*>(row + 1024 + (by >> 2) + 4 * g2) = o;
        } else {                           // odd: m = by+8g3+2e+1
            const int g3 = g - 8;
            o.x = f2bf(tile[8 * g3 + 1][n]);
            o.y = f2bf(tile[8 * g3 + 3][n]);
            o.z = f2bf(tile[8 * g3 + 5][n]);
            o.w = f2bf(tile[8 * g3 + 7][n]);
            *reinterpret_cast<ushort4*>(row + 2048 + (by >> 1) + 4 * g3) = o;
        }
    }
}

// ---------------------------------------------------------------------------
// W12 [1024][2048]: col<1024: trig(pi*k*(2u+1)/2048), k=col  (size-1024 xform)
//                   col>=1024: trig(pi*(2j+1)*(2u+1)/4096), j=col-1024
// ---------------------------------------------------------------------------
__global__ __launch_bounds__(256) void gen_w12(
    unsigned short* __restrict__ out, int doSin)
{
    const int flat = (int)(((size_t)blockIdx.x * 256 + threadIdx.x) * 4);
    const int u  = flat >> 11;
    const int c0 = flat & 2047;
    const unsigned int step = 2u * (unsigned int)u + 1u;
    unsigned short o[4];
#pragma unroll
    for (int j = 0; j < 4; ++j) {
        const int c = c0 + j;
        float ang;
        if (c < 1024) {
            unsigned int p = ((unsigned int)c * step) & 4095u;
            ang = (float)p * (3.14159265358979323846f / 2048.0f);
        } else {
            unsigned int p = ((unsigned int)(2 * (c - 1024) + 1) * step) & 8191u;
            ang = (float)p * (3.14159265358979323846f / 4096.0f);
        }
        o[j] = f2bf(doSin ? __sinf(ang) : __cosf(ang));
    }
    uint2 pack;
    pack.x = (unsigned int)o[0] | ((unsigned int)o[1] << 16);
    pack.y = (unsigned int)o[2] | ((unsigned int)o[3] << 16);
    *reinterpret_cast<uint2*>(out + flat) = pack;
}

// WO [2048][2048]: trig(pi*(2j+1)*(2u+1)/8192)
__global__ __launch_bounds__(256) void gen_wO(
    unsigned short* __restrict__ out, int doSin)
{
    const int flat = (int)(((size_t)blockIdx.x * 256 + threadIdx.x) * 4);
    const int u  = flat >> 11;
    const int c0 = flat & 2047;
    const unsigned int step = 2u * (unsigned int)u + 1u;
    unsigned short o[4];
#pragma unroll
    for (int j = 0; j < 4; ++j) {
        unsigned int p = ((unsigned int)(2 * (c0 + j) + 1) * step) & 16383u;
        float ang = (float)p * (3.14159265358979323846f / 8192.0f);
        o[j] = f2bf(doSin ? __sinf(ang) : __cosf(ang));
    }
    uint2 pack;
    pack.x = (unsigned int)o[0] | ((unsigned int)o[1] << 16);
    pack.y = (unsigned int)o[2] | ((unsigned int)o[3] << 16);
    *reinterpret_cast<uint2*>(out + flat) = pack;
}

#define BARRIER __builtin_amdgcn_s_barrier()
#define LGKM0 asm volatile("s_waitcnt lgkmcnt(0)" ::: "memory")
#define VM0 asm volatile("s_waitcnt vmcnt(0)" ::: "memory")
#define PRIO1 __builtin_amdgcn_s_setprio(1)
#define PRIO0 __builtin_amdgcn_s_setprio(0)

// ---------------------------------------------------------------------------
// SMALL fused dual-acc GEMM: tile 128(P) x 64(Q), K=1024 per acc (cols 0..1023
// = E2 weights/data, 1024..2047 = O2). 4 waves (2x2), wave 64x32.
// EPI=1 (stage1, sin): E[i][j]=aE+aO ; E[2047-i][j]=aO-aE   (E ld 4096)
// EPI=2 (stage2, cos): E[i][j]=aE+aO ; E[i][2047-j]=aE-aO   (E ld 2048)
// LDS ring-2 x 3 units = 48 KiB -> 2 blocks/CU.
// ---------------------------------------------------------------------------
#define S_STAGE(LB, KC) do { \
    _Pragma("unroll") for (int p = 0; p < 6; ++p) \
        async16(srcp_[p] + (KC), &lds[(LB) + ((p * 256 + wbase) * 8)]); } while (0)

#define S_LD(LB) do { \
    _Pragma("unroll") for (int mm = 0; mm < 4; ++mm) { \
        af[mm][0] = *(const bf16x8*)&lds[(LB) + aOff + mm * 1024 + sl0]; \
        af[mm][1] = *(const bf16x8*)&lds[(LB) + aOff + mm * 1024 + sl1]; } \
    _Pragma("unroll") for (int nn = 0; nn < 2; ++nn) { \
        bfr[nn][0] = *(const bf16x8*)&lds[(LB) + bOff + nn * 1024 + sl0]; \
        bfr[nn][1] = *(const bf16x8*)&lds[(LB) + bOff + nn * 1024 + sl1]; } } while (0)

#define S_MFMA(ACC) do { \
    _Pragma("unroll") for (int ks = 0; ks < 2; ++ks) \
    _Pragma("unroll") for (int mm = 0; mm < 4; ++mm) \
    _Pragma("unroll") for (int nn = 0; nn < 2; ++nn) \
        ACC[mm][nn] = __builtin_amdgcn_mfma_f32_16x16x32_bf16( \
            af[mm][ks], bfr[nn][ks], ACC[mm][nn], 0, 0, 0); } while (0)

template <int EPI>
__global__ __launch_bounds__(256, 2) void gemm_small(
    const unsigned short* __restrict__ P,
    const unsigned short* __restrict__ Q,
    unsigned short* __restrict__ E,
    int ldp, int ldq, int nbx)
{
    __shared__ __align__(16) unsigned short lds[2 * 3 * 4096];   // 48 KiB

    const int tid  = threadIdx.x;
    const int lane = tid & 63;
    const int w    = tid >> 6;
    const int wm   = w >> 1;
    const int wn   = w & 1;

    const int bid = blockIdx.x;
    const int wg  = (bid & 7) * (gridDim.x >> 3) + (bid >> 3);
    const int brow = (wg / nbx) * 128;
    const int bcol = (wg % nbx) * 64;

    const unsigned short* srcp_[6];
    const int wbase = tid & ~63;
#pragma unroll
    for (int p = 0; p < 6; ++p) {
        const int c    = p * 256 + tid;
        const int unit = c >> 9;          // 0,1 = P ; 2 = Q
        const int urow = (c >> 3) & 63;
        const int slot = c & 7;
        const int sx   = (slot ^ (urow & 7)) << 3;
        srcp_[p] = (unit < 2)
            ? P + (size_t)(brow + unit * 64 + urow) * ldp + sx
            : Q + (size_t)(bcol + urow) * ldq + sx;
    }

    const int lr = lane & 15, lk = lane >> 4, sx = lr & 7;
    const int sl0 = ((lk) ^ sx) << 3;
    const int sl1 = ((4 + lk) ^ sx) << 3;
    const int aOff = wm * 4096 + lr * 64;
    const int bOff = 2 * 4096 + wn * 2048 + lr * 64;

    bf16x8 af[4][2], bfr[2][2];
    f32x4 aE[4][2] = {};
    f32x4 aO[4][2] = {};

    S_STAGE(0, 0);
    VM0;
    BARRIER;

    for (int t = 0; t < 16; ++t) {
        const int lb = (t & 1) ? 12288 : 0;
        S_STAGE(lb ^ 12288, (t + 1) << 6);
        S_LD(lb);
        PRIO1; S_MFMA(aE); PRIO0;
        LGKM0; VM0; BARRIER;
    }
    for (int t = 16; t < 31; ++t) {
        const int lb = (t & 1) ? 12288 : 0;
        S_STAGE(lb ^ 12288, (t + 1) << 6);
        S_LD(lb);
        PRIO1; S_MFMA(aO); PRIO0;
        LGKM0; VM0; BARRIER;
    }
    {
        S_LD(12288);
        PRIO1; S_MFMA(aO); PRIO0;
    }

    const int r0 = brow + wm * 64 + (lane >> 4) * 4;
    const int c0 = bcol + wn * 32 + (lane & 15);
#pragma unroll
    for (int mf = 0; mf < 4; ++mf)
#pragma unroll
        for (int nf = 0; nf < 2; ++nf)
#pragma unroll
            for (int r = 0; r < 4; ++r) {
                const int i = r0 + mf * 16 + r;
                const int j = c0 + nf * 16;
                const float e2 = aE[mf][nf][r];
                const float o2 = aO[mf][nf][r];
                if (EPI == 1) {          // sin: reflect P-row
                    E[(size_t)i * 4096 + j] = f2bf(e2 + o2);
                    E[(size_t)(2047 - i) * 4096 + j] = f2bf(o2 - e2);
                } else {                 // cos: reflect Q-col
                    E[(size_t)i * 2048 + j] = f2bf(e2 + o2);
                    E[(size_t)i * 2048 + 2047 - j] = f2bf(e2 - o2);
                }
            }
}

// ---------------------------------------------------------------------------
// BIG single-acc GEMM + level-1 butterfly epilogue (reads E from global):
// tile 128x128, K=2048 (32 tiles). 4 waves, wave 64x64.
// EPI=1: O=acc; e=E1[i][j]; T[i][pi4(j)]=e+O ; T[4095-i][pi4(j)]=O-e  (bf16)
// EPI=2: O=acc; e=Es2[i][j]; out[i][j]=e+O ; out[i][4095-j]=e-O      (f32)
// LDS ring-2 x 4 units = 64 KiB -> 2 blocks/CU.
// ---------------------------------------------------------------------------
#define B_STAGE(LB, KC) do { \
    _Pragma("unroll") for (int p = 0; p < 8; ++p) \
        async16(srcp_[p] + (KC), &lds[(LB) + ((p * 256 + wbase) * 8)]); } while (0)

#define B_LD(LB) do { \
    _Pragma("unroll") for (int mm = 0; mm < 4; ++mm) { \
        af[mm][0] = *(const bf16x8*)&lds[(LB) + aOff + mm * 1024 + sl0]; \
        af[mm][1] = *(const bf16x8*)&lds[(LB) + aOff + mm * 1024 + sl1]; } \
    _Pragma("unroll") for (int nn = 0; nn < 4; ++nn) { \
        bfr[nn][0] = *(const bf16x8*)&lds[(LB) + bOff + nn * 1024 + sl0]; \
        bfr[nn][1] = *(const bf16x8*)&lds[(LB) + bOff + nn * 1024 + sl1]; } } while (0)

#define B_MFMA(ACC) do { \
    _Pragma("unroll") for (int ks = 0; ks < 2; ++ks) \
    _Pragma("unroll") for (int mm = 0; mm < 4; ++mm) \
    _Pragma("unroll") for (int nn = 0; nn < 4; ++nn) \
        ACC[mm][nn] = __builtin_amdgcn_mfma_f32_16x16x32_bf16( \
            af[mm][ks], bfr[nn][ks], ACC[mm][nn], 0, 0, 0); } while (0)

template <int EPI, typename OutT>
__global__ __launch_bounds__(256, 2) void gemm_big(
    const unsigned short* __restrict__ P,
    const unsigned short* __restrict__ Q,
    OutT* __restrict__ C,
    const unsigned short* __restrict__ E,
    int ldp, int ldq, int nbx)
{
    __shared__ __align__(16) unsigned short lds[2 * 4 * 4096];   // 64 KiB

    const int tid  = threadIdx.x;
    const int lane = tid & 63;
    const int w    = tid >> 6;
    const int wm   = w >> 1;
    const int wn   = w & 1;

    const int bid = blockIdx.x;
    const int wg  = (bid & 7) * (gridDim.x >> 3) + (bid >> 3);
    const int brow = (wg / nbx) * 128;
    const int bcol = (wg % nbx) * 128;

    const unsigned short* srcp_[8];
    const int wbase = tid & ~63;
#pragma unroll
    for (int p = 0; p < 8; ++p) {
        const int c    = p * 256 + tid;
        const int unit = c >> 9;          // 0,1 = P ; 2,3 = Q
        const int urow = (c >> 3) & 63;
        const int slot = c & 7;
        const int sx   = (slot ^ (urow & 7)) << 3;
        srcp_[p] = (unit < 2)
            ? P + (size_t)(brow + unit * 64 + urow) * ldp + sx
            : Q + (size_t)(bcol + (unit - 2) * 64 + urow) * ldq + sx;
    }

    const int lr = lane & 15, lk = lane >> 4, sx = lr & 7;
    const int sl0 = ((lk) ^ sx) << 3;
    const int sl1 = ((4 + lk) ^ sx) << 3;
    const int aOff = wm * 4096 + lr * 64;
    const int bOff = (2 + wn) * 4096 + lr * 64;

    bf16x8 af[4][2], bfr[4][2];
    f32x4 acc[4][4] = {};

    B_STAGE(0, 0);
    VM0;
    BARRIER;

    for (int t = 0; t < 31; ++t) {
        const int lb = (t & 1) << 14;
        B_STAGE(lb ^ 16384, (t + 1) << 6);
        B_LD(lb);
        PRIO1; B_MFMA(acc); PRIO0;
        LGKM0; VM0; BARRIER;
    }
    {
        B_LD(16384);
        PRIO1; B_MFMA(acc); PRIO0;
    }

    const int r0 = brow + wm * 64 + (lane >> 4) * 4;
    const int c0 = bcol + wn * 64 + (lane & 15);
#pragma unroll
    for (int mf = 0; mf < 4; ++mf)
#pragma unroll
        for (int nf = 0; nf < 4; ++nf)
#pragma unroll
            for (int r = 0; r < 4; ++r) {
                const int i = r0 + mf * 16 + r;
                const int j = c0 + nf * 16;
                const float o = acc[mf][nf][r];
                if (EPI == 1) {
                    const float e = bf2f(E[(size_t)i * 4096 + j]);
                    const int pin = (j & 1) ? 2048 + (j >> 1)
                                  : ((j & 2) ? 1024 + (j >> 2) : (j >> 2));
                    ((unsigned short*)C)[(size_t)i * 4096 + pin] = f2bf(e + o);
                    ((unsigned short*)C)[(size_t)(4095 - i) * 4096 + pin] = f2bf(o - e);
                } else {
                    const float e = bf2f(E[(size_t)i * 2048 + j]);
                    ((float*)C)[(size_t)i * 4096 + j] = e + o;
                    ((float*)C)[(size_t)i * 4096 + 4095 - j] = e - o;
                }
            }
}

// ---------------------------------------------------------------------------
// launch. Two-level even/odd recursion (103 GFLOP vs 137):
// stage1 (IDXST rows): small: E1 = bf2(sin_1024, sin_oddev) [2048][4096]
//                      big:   T  = bf1(E1, sin_odd)  -> pi4-packed cols
// stage2 (IDCT cols):  small: Es2 = bf2(cos_1024, cos_oddev) [4096][2048]
//                      big:   out = bf1(Es2, cos_odd) f32
// ws: Xt 32MB | T 32MB | E 16MB | W12 4MB | WO 8MB = 92MB
// ---------------------------------------------------------------------------
extern "C" void kernel_launch(void* const* d_in, const int* in_sizes, int n_in,
                              void* d_out, int out_size, void* d_ws, size_t ws_size,
                              hipStream_t stream) {
    const float* X = (const float*)d_in[0];

    unsigned short* Xt  = (unsigned short*)d_ws;                 // [4096][4096]
    unsigned short* T   = Xt + (size_t)4096 * 4096;              // [4096][4096]
    unsigned short* E   = T + (size_t)4096 * 4096;               // [2048][4096] / [4096][2048]
    unsigned short* W12 = E + (size_t)2048 * 4096;               // [1024][2048]
    unsigned short* WO  = W12 + (size_t)1024 * 2048;             // [2048][2048]

    transpose_perm4<<<dim3(64, 64), 256, 0, stream>>>(X, Xt);

    gen_w12<<<2048, 256, 0, stream>>>(W12, 1);
    gen_wO<<<4096, 256, 0, stream>>>(WO, 1);
    gemm_small<1><<<512, 256, 0, stream>>>(W12, Xt, E, 2048, 4096, 64);
    gemm_big<1, unsigned short><<<512, 256, 0, stream>>>(WO, Xt + 2048, T, E, 2048, 4096, 32);

    gen_w12<<<2048, 256, 0, stream>>>(W12, 0);
    gen_wO<<<4096, 256, 0, stream>>>(WO, 0);
    gemm_small<2><<<512, 256, 0, stream>>>(T, W12, E, 4096, 2048, 16);
    gemm_big<2, float><<<512, 256, 0, stream>>>(T + 2048, WO, (float*)d_out, E, 4096, 2048, 16);
}